// Round 1
// baseline (237.549 us; speedup 1.0000x reference)
//
#include <hip/hip_runtime.h>
#include <hip/hip_bf16.h>

typedef unsigned short u16;
typedef __bf16 bf16x8 __attribute__((ext_vector_type(8)));
typedef float f32x4 __attribute__((ext_vector_type(4)));

#define LOG2E 1.4426950408889634f

// B=2, T=2048, C=1024, H=16, hd=64, 3C=3072. scale = C^-0.5 = 1/32 (exact pow2).

__device__ __forceinline__ u16 f2b(float f) {
  unsigned x = __float_as_uint(f);
  unsigned r = (x + 0x7fffu + ((x >> 16) & 1u)) >> 16;  // RNE
  return (u16)r;
}

__device__ __forceinline__ void gll16(const void* g, void* l) {
  __builtin_amdgcn_global_load_lds((const __attribute__((address_space(1))) void*)g,
                                   (__attribute__((address_space(3))) void*)l, 16, 0, 0);
}

__device__ __forceinline__ f32x4 mfma16(bf16x8 a, bf16x8 b, f32x4 c) {
  return __builtin_amdgcn_mfma_f32_16x16x32_bf16(a, b, c, 0, 0, 0);
}

// ---------------- fp32 -> bf16 convert ----------------
__global__ __launch_bounds__(256) void cvt_bf16(const float* __restrict__ src,
                                                u16* __restrict__ dst, int n) {
  int i = (blockIdx.x * 256 + threadIdx.x) * 4;
  if (i >= n) return;
  float4 v = *(const float4*)(src + i);
  ushort4 o;
  o.x = f2b(v.x); o.y = f2b(v.y); o.z = f2b(v.z); o.w = f2b(v.w);
  *(ushort4*)(dst + i) = o;
}

// ---------------- GEMM1: qkv = x @ w_attn^T + b_attn, scatter to Q/K/Vt ----------------
// A: [4096][1024] bf16 (x), W: [3072][1024] bf16. 128x128 tile, BK=64.
// Q layout [b][h][t][64] (pre-scaled by 1/32), K layout [b][h][t][64], Vt layout [b][h][64][t]
__global__ __launch_bounds__(256) void gemm_qkv(const u16* __restrict__ A,
                                                const u16* __restrict__ W,
                                                const float* __restrict__ bias,
                                                u16* __restrict__ Qb,
                                                u16* __restrict__ Kb,
                                                u16* __restrict__ Vtb) {
  __shared__ u16 As[128 * 64];
  __shared__ u16 Bs[128 * 64];
  const int K = 1024;
  int bn = blockIdx.x, bm = blockIdx.y;
  int tid = threadIdx.x, lane = tid & 63, w = tid >> 6;
  int wm = w >> 1, wn = w & 1, g = lane >> 4, c = lane & 15;
  f32x4 acc[4][4] = {};
  const u16* Arow = A + (size_t)(bm * 128) * K;
  const u16* Wrow = W + (size_t)(bn * 128) * K;
  for (int k0 = 0; k0 < K; k0 += 64) {
#pragma unroll
    for (int rr = 0; rr < 4; ++rr) {
      int ci = rr * 256 + tid;
      gll16(Arow + (ci >> 3) * K + k0 + (ci & 7) * 8, As + ci * 8);
    }
#pragma unroll
    for (int rr = 0; rr < 4; ++rr) {
      int ci = rr * 256 + tid;
      gll16(Wrow + (ci >> 3) * K + k0 + (ci & 7) * 8, Bs + ci * 8);
    }
    __syncthreads();
#pragma unroll
    for (int kk = 0; kk < 2; ++kk) {
      int koff = kk * 32 + g * 8;
      bf16x8 af[4], bfr[4];
#pragma unroll
      for (int mi = 0; mi < 4; ++mi)
        af[mi] = *(const bf16x8*)&As[(wm * 64 + mi * 16 + c) * 64 + koff];
#pragma unroll
      for (int ni = 0; ni < 4; ++ni)
        bfr[ni] = *(const bf16x8*)&Bs[(wn * 64 + ni * 16 + c) * 64 + koff];
#pragma unroll
      for (int mi = 0; mi < 4; ++mi)
#pragma unroll
        for (int ni = 0; ni < 4; ++ni)
          acc[mi][ni] = mfma16(af[mi], bfr[ni], acc[mi][ni]);
    }
    __syncthreads();
  }
  // epilogue: row -> (b,t), col -> (h, j) with j in [0,192): q<64, k<128, v<192
#pragma unroll
  for (int mi = 0; mi < 4; ++mi)
#pragma unroll
    for (int ni = 0; ni < 4; ++ni)
#pragma unroll
      for (int r = 0; r < 4; ++r) {
        int row = bm * 128 + wm * 64 + mi * 16 + g * 4 + r;
        int col = bn * 128 + wn * 64 + ni * 16 + c;
        float v = acc[mi][ni][r] + bias[col];
        int b = row >> 11, t = row & 2047;
        int h = col / 192, j = col - h * 192;
        int bh = b * 16 + h;
        if (j < 64) {
          Qb[((size_t)bh * 2048 + t) * 64 + j] = f2b(v * 0.03125f);
        } else if (j < 128) {
          Kb[((size_t)bh * 2048 + t) * 64 + (j - 64)] = f2b(v);
        } else {
          Vtb[((size_t)bh * 64 + (j - 128)) * 2048 + t] = f2b(v);
        }
      }
}

// ---------------- Flash attention (NO causal mask, full softmax) ----------------
// grid: (T/128, B*H). 4 waves; wave w owns q rows [w*32, w*32+32).
__global__ __launch_bounds__(256) void attn_kernel(const u16* __restrict__ Qb,
                                                   const u16* __restrict__ Kb,
                                                   const u16* __restrict__ Vtb,
                                                   u16* __restrict__ Yb) {
  __shared__ u16 Ks[64 * 64];    // [t_local][d]
  __shared__ u16 Vs[64 * 64];    // [d][t_local]
  __shared__ u16 Ps[128 * 64];   // [q_local][t_local], per-wave disjoint rows
  int bh = blockIdx.y;
  int b = bh >> 4, h = bh & 15;
  int q0 = blockIdx.x * 128;
  const u16* Qh = Qb + (size_t)bh * 2048 * 64;
  const u16* Kh = Kb + (size_t)bh * 2048 * 64;
  const u16* Vh = Vtb + (size_t)bh * 64 * 2048;
  int tid = threadIdx.x, lane = tid & 63, w = tid >> 6, g = lane >> 4, c = lane & 15;

  bf16x8 qf[2][2];
#pragma unroll
  for (int rb = 0; rb < 2; ++rb)
#pragma unroll
    for (int kk = 0; kk < 2; ++kk)
      qf[rb][kk] = *(const bf16x8*)&Qh[(q0 + w * 32 + rb * 16 + c) * 64 + kk * 32 + g * 8];

  f32x4 acc[2][4] = {};
  float mx[2][4], ls[2][4];
#pragma unroll
  for (int rb = 0; rb < 2; ++rb)
#pragma unroll
    for (int r = 0; r < 4; ++r) { mx[rb][r] = -1e30f; ls[rb][r] = 0.f; }

  for (int t0 = 0; t0 < 2048; t0 += 64) {
    // stage K tile (rows t, contiguous d) and V tile (rows d, contiguous t)
#pragma unroll
    for (int rr = 0; rr < 2; ++rr) {
      int ci = rr * 256 + tid;
      gll16(Kh + (size_t)(t0 + (ci >> 3)) * 64 + (ci & 7) * 8, Ks + ci * 8);
      gll16(Vh + (size_t)(ci >> 3) * 2048 + t0 + (ci & 7) * 8, Vs + ci * 8);
    }
    __syncthreads();

    // S = Q K^T (scale already folded into Q)
    f32x4 s[2][4] = {};
#pragma unroll
    for (int kk = 0; kk < 2; ++kk) {
      int koff = kk * 32 + g * 8;
      bf16x8 kf[4];
#pragma unroll
      for (int nb = 0; nb < 4; ++nb)
        kf[nb] = *(const bf16x8*)&Ks[(nb * 16 + c) * 64 + koff];
#pragma unroll
      for (int rb = 0; rb < 2; ++rb)
#pragma unroll
        for (int nb = 0; nb < 4; ++nb)
          s[rb][nb] = mfma16(qf[rb][kk], kf[nb], s[rb][nb]);
    }

    // online softmax per q-row; row = (g*4 + r), cols spread over 16 lanes x 4 frags
#pragma unroll
    for (int rb = 0; rb < 2; ++rb)
#pragma unroll
      for (int r = 0; r < 4; ++r) {
        float tm = fmaxf(fmaxf(s[rb][0][r], s[rb][1][r]), fmaxf(s[rb][2][r], s[rb][3][r]));
        tm = fmaxf(tm, __shfl_xor(tm, 1));
        tm = fmaxf(tm, __shfl_xor(tm, 2));
        tm = fmaxf(tm, __shfl_xor(tm, 4));
        tm = fmaxf(tm, __shfl_xor(tm, 8));
        float mo = mx[rb][r];
        float mn = fmaxf(mo, tm);
        float corr = exp2f((mo - mn) * LOG2E);
        float ps = 0.f;
        int prow = (w * 32 + rb * 16 + g * 4 + r) * 64;
#pragma unroll
        for (int nb = 0; nb < 4; ++nb) {
          float p = exp2f((s[rb][nb][r] - mn) * LOG2E);
          ps += p;
          Ps[prow + nb * 16 + c] = f2b(p);
        }
        mx[rb][r] = mn;
        ls[rb][r] = ls[rb][r] * corr + ps;  // per-lane partial sum; reduced at end
#pragma unroll
        for (int db = 0; db < 4; ++db) acc[rb][db][r] *= corr;
      }

    // Y += P V   (P rows read back from own wave's LDS region; no barrier needed)
#pragma unroll
    for (int kk = 0; kk < 2; ++kk) {
      int koff = kk * 32 + g * 8;
      bf16x8 pf[2];
#pragma unroll
      for (int rb = 0; rb < 2; ++rb)
        pf[rb] = *(const bf16x8*)&Ps[(w * 32 + rb * 16 + c) * 64 + koff];
#pragma unroll
      for (int db = 0; db < 4; ++db) {
        bf16x8 vf = *(const bf16x8*)&Vs[(db * 16 + c) * 64 + koff];
#pragma unroll
        for (int rb = 0; rb < 2; ++rb)
          acc[rb][db] = mfma16(pf[rb], vf, acc[rb][db]);
      }
    }
    __syncthreads();  // protect Ks/Vs before next tile's staging
  }

  // epilogue: y = acc / l ; Yb layout [b][t][h*64+d] bf16
#pragma unroll
  for (int rb = 0; rb < 2; ++rb)
#pragma unroll
    for (int r = 0; r < 4; ++r) {
      float lt = ls[rb][r];
      lt += __shfl_xor(lt, 1);
      lt += __shfl_xor(lt, 2);
      lt += __shfl_xor(lt, 4);
      lt += __shfl_xor(lt, 8);
      float inv = 1.0f / lt;
      int trow = q0 + w * 32 + rb * 16 + g * 4 + r;
      size_t base = ((size_t)b * 2048 + trow) * 1024 + h * 64;
#pragma unroll
      for (int db = 0; db < 4; ++db)
        Yb[base + db * 16 + c] = f2b(acc[rb][db][r] * inv);
    }
}

// ---------------- GEMM3: out = y @ w_proj^T + b_proj (fp32 out) ----------------
__global__ __launch_bounds__(256) void gemm_proj(const u16* __restrict__ A,
                                                 const u16* __restrict__ W,
                                                 const float* __restrict__ bias,
                                                 float* __restrict__ out) {
  __shared__ u16 As[128 * 64];
  __shared__ u16 Bs[128 * 64];
  const int K = 1024;
  int bn = blockIdx.x, bm = blockIdx.y;
  int tid = threadIdx.x, lane = tid & 63, w = tid >> 6;
  int wm = w >> 1, wn = w & 1, g = lane >> 4, c = lane & 15;
  f32x4 acc[4][4] = {};
  const u16* Arow = A + (size_t)(bm * 128) * K;
  const u16* Wrow = W + (size_t)(bn * 128) * K;
  for (int k0 = 0; k0 < K; k0 += 64) {
#pragma unroll
    for (int rr = 0; rr < 4; ++rr) {
      int ci = rr * 256 + tid;
      gll16(Arow + (ci >> 3) * K + k0 + (ci & 7) * 8, As + ci * 8);
    }
#pragma unroll
    for (int rr = 0; rr < 4; ++rr) {
      int ci = rr * 256 + tid;
      gll16(Wrow + (ci >> 3) * K + k0 + (ci & 7) * 8, Bs + ci * 8);
    }
    __syncthreads();
#pragma unroll
    for (int kk = 0; kk < 2; ++kk) {
      int koff = kk * 32 + g * 8;
      bf16x8 af[4], bfr[4];
#pragma unroll
      for (int mi = 0; mi < 4; ++mi)
        af[mi] = *(const bf16x8*)&As[(wm * 64 + mi * 16 + c) * 64 + koff];
#pragma unroll
      for (int ni = 0; ni < 4; ++ni)
        bfr[ni] = *(const bf16x8*)&Bs[(wn * 64 + ni * 16 + c) * 64 + koff];
#pragma unroll
      for (int mi = 0; mi < 4; ++mi)
#pragma unroll
        for (int ni = 0; ni < 4; ++ni)
          acc[mi][ni] = mfma16(af[mi], bfr[ni], acc[mi][ni]);
    }
    __syncthreads();
  }
#pragma unroll
  for (int mi = 0; mi < 4; ++mi)
#pragma unroll
    for (int ni = 0; ni < 4; ++ni)
#pragma unroll
      for (int r = 0; r < 4; ++r) {
        int row = bm * 128 + wm * 64 + mi * 16 + g * 4 + r;
        int col = bn * 128 + wn * 64 + ni * 16 + c;
        out[(size_t)row * 1024 + col] = acc[mi][ni][r] + bias[col];
      }
}

extern "C" void kernel_launch(void* const* d_in, const int* in_sizes, int n_in,
                              void* d_out, int out_size, void* d_ws, size_t ws_size,
                              hipStream_t stream) {
  const float* x      = (const float*)d_in[0];  // [2,2048,1024]
  const float* w_attn = (const float*)d_in[1];  // [3072,1024]
  const float* b_attn = (const float*)d_in[2];  // [3072]
  const float* w_proj = (const float*)d_in[3];  // [1024,1024]
  const float* b_proj = (const float*)d_in[4];  // [1024]
  float* out = (float*)d_out;

  u16* ws = (u16*)d_ws;
  // workspace layout (u16 elements)
  const size_t XB  = 0;                 // 4096*1024
  const size_t WAB = XB + 4194304;      // 3072*1024
  const size_t WPB = WAB + 3145728;     // 1024*1024
  const size_t QB  = WPB + 1048576;     // 2*16*2048*64
  const size_t KB  = QB + 4194304;
  const size_t VTB = KB + 4194304;      // [bh][64][2048]
  const size_t YB  = VTB + 4194304;     // 4096*1024
  // total = 25165824 u16 = 48 MB

  cvt_bf16<<<4096, 256, 0, stream>>>(x, ws + XB, 4194304);
  cvt_bf16<<<3072, 256, 0, stream>>>(w_attn, ws + WAB, 3145728);
  cvt_bf16<<<1024, 256, 0, stream>>>(w_proj, ws + WPB, 1048576);

  gemm_qkv<<<dim3(24, 32), 256, 0, stream>>>(ws + XB, ws + WAB, b_attn,
                                             ws + QB, ws + KB, ws + VTB);

  attn_kernel<<<dim3(16, 32), 256, 0, stream>>>(ws + QB, ws + KB, ws + VTB, ws + YB);

  gemm_proj<<<dim3(8, 32), 256, 0, stream>>>(ws + YB, ws + WPB, b_proj, out);
}

// Round 2
// 190.013 us; speedup vs baseline: 1.2502x; 1.2502x over previous
//
#include <hip/hip_runtime.h>
#include <hip/hip_bf16.h>

typedef unsigned short u16;
typedef __bf16 bf16x8 __attribute__((ext_vector_type(8)));
typedef float f32x4 __attribute__((ext_vector_type(4)));

// B=2, T=2048, C=1024, H=16, hd=64. scale = 1/32; log2(e)/32 folded into Q.
#define QSCALE 0.045084220027780106f

__device__ __forceinline__ u16 f2b(float f) {
  unsigned x = __float_as_uint(f);
  unsigned r = (x + 0x7fffu + ((x >> 16) & 1u)) >> 16;  // RNE
  return (u16)r;
}

__device__ __forceinline__ void gll16(const void* g, void* l) {
  __builtin_amdgcn_global_load_lds((const __attribute__((address_space(1))) void*)g,
                                   (__attribute__((address_space(3))) void*)l, 16, 0, 0);
}

__device__ __forceinline__ f32x4 mfma16(bf16x8 a, bf16x8 b, f32x4 c) {
  return __builtin_amdgcn_mfma_f32_16x16x32_bf16(a, b, c, 0, 0, 0);
}

// ---------------- fp32 -> bf16 convert (all three tensors, one launch) ----------------
__global__ __launch_bounds__(256) void cvt3(const float* __restrict__ x,
                                            const float* __restrict__ wa,
                                            const float* __restrict__ wp,
                                            u16* __restrict__ dx,
                                            u16* __restrict__ dwa,
                                            u16* __restrict__ dwp) {
  const int N1 = 4194304, N2 = 3145728;  // x, w_attn; w_proj = 1048576
  int i = (blockIdx.x * 256 + threadIdx.x) * 4;
  const float* s;
  u16* d;
  int off;
  if (i < N1) { s = x; d = dx; off = i; }
  else if (i < N1 + N2) { s = wa; d = dwa; off = i - N1; }
  else { s = wp; d = dwp; off = i - N1 - N2; }
  float4 v = *(const float4*)(s + off);
  ushort4 o;
  o.x = f2b(v.x); o.y = f2b(v.y); o.z = f2b(v.z); o.w = f2b(v.w);
  *(ushort4*)(d + off) = o;
}

// ---------------- GEMM1: qkv = x @ w_attn^T + b_attn, scatter to Q/K/Vt ----------------
// Q layout [b][h][t][64] (pre-scaled by log2e/32), K layout [b][h][t][64], Vt layout [b][h][64][t]
__global__ __launch_bounds__(256) void gemm_qkv(const u16* __restrict__ A,
                                                const u16* __restrict__ W,
                                                const float* __restrict__ bias,
                                                u16* __restrict__ Qb,
                                                u16* __restrict__ Kb,
                                                u16* __restrict__ Vtb) {
  __shared__ u16 As[128 * 64];
  __shared__ u16 Bs[128 * 64];
  const int K = 1024;
  int bn = blockIdx.x, bm = blockIdx.y;
  int tid = threadIdx.x, lane = tid & 63, w = tid >> 6;
  int wm = w >> 1, wn = w & 1, g = lane >> 4, c = lane & 15;
  f32x4 acc[4][4] = {};
  const u16* Arow = A + (size_t)(bm * 128) * K;
  const u16* Wrow = W + (size_t)(bn * 128) * K;
  for (int k0 = 0; k0 < K; k0 += 64) {
#pragma unroll
    for (int rr = 0; rr < 4; ++rr) {
      int ci = rr * 256 + tid;
      gll16(Arow + (ci >> 3) * K + k0 + (ci & 7) * 8, As + ci * 8);
    }
#pragma unroll
    for (int rr = 0; rr < 4; ++rr) {
      int ci = rr * 256 + tid;
      gll16(Wrow + (ci >> 3) * K + k0 + (ci & 7) * 8, Bs + ci * 8);
    }
    __syncthreads();
#pragma unroll
    for (int kk = 0; kk < 2; ++kk) {
      int koff = kk * 32 + g * 8;
      bf16x8 af[4], bfr[4];
#pragma unroll
      for (int mi = 0; mi < 4; ++mi)
        af[mi] = *(const bf16x8*)&As[(wm * 64 + mi * 16 + c) * 64 + koff];
#pragma unroll
      for (int ni = 0; ni < 4; ++ni)
        bfr[ni] = *(const bf16x8*)&Bs[(wn * 64 + ni * 16 + c) * 64 + koff];
#pragma unroll
      for (int mi = 0; mi < 4; ++mi)
#pragma unroll
        for (int ni = 0; ni < 4; ++ni)
          acc[mi][ni] = mfma16(af[mi], bfr[ni], acc[mi][ni]);
    }
    __syncthreads();
  }
#pragma unroll
  for (int mi = 0; mi < 4; ++mi)
#pragma unroll
    for (int ni = 0; ni < 4; ++ni)
#pragma unroll
      for (int r = 0; r < 4; ++r) {
        int row = bm * 128 + wm * 64 + mi * 16 + g * 4 + r;
        int col = bn * 128 + wn * 64 + ni * 16 + c;
        float v = acc[mi][ni][r] + bias[col];
        int b = row >> 11, t = row & 2047;
        int h = col / 192, j = col - h * 192;
        int bh = b * 16 + h;
        if (j < 64) {
          Qb[((size_t)bh * 2048 + t) * 64 + j] = f2b(v * QSCALE);
        } else if (j < 128) {
          Kb[((size_t)bh * 2048 + t) * 64 + (j - 64)] = f2b(v);
        } else {
          Vtb[((size_t)bh * 64 + (j - 128)) * 2048 + t] = f2b(v);
        }
      }
}

// ---------------- Flash attention (full softmax, no mask) ----------------
// grid: (T/64, B*H). 4 waves; wave w owns q rows [w*16, w*16+16).
// LDS K/V tiles XOR-swizzled: linear slot (row, seg16B) holds global seg^(row&7).
__global__ __launch_bounds__(256, 4) void attn_kernel(const u16* __restrict__ Qb,
                                                      const u16* __restrict__ Kb,
                                                      const u16* __restrict__ Vtb,
                                                      u16* __restrict__ Yb) {
  __shared__ u16 Ks[2][64 * 64];  // [t_local][d] swizzled
  __shared__ u16 Vs[2][64 * 64];  // [d][t_local] swizzled
  __shared__ u16 Ps[64 * 64];     // [q_local][t_local] swizzled, per-wave rows
  int bh = blockIdx.y;
  int b = bh >> 4, h = bh & 15;
  int q0 = blockIdx.x * 64;
  const u16* Qh = Qb + (size_t)bh * 2048 * 64;
  const u16* Kh = Kb + (size_t)bh * 2048 * 64;
  const u16* Vh = Vtb + (size_t)bh * 64 * 2048;
  int tid = threadIdx.x, lane = tid & 63, w = tid >> 6, g = lane >> 4, c = lane & 15;

  bf16x8 qf[2];
#pragma unroll
  for (int kk = 0; kk < 2; ++kk)
    qf[kk] = *(const bf16x8*)&Qh[(q0 + w * 16 + c) * 64 + kk * 32 + g * 8];

  f32x4 acc[4] = {};
  float mx[4], ls[4];
#pragma unroll
  for (int r = 0; r < 4; ++r) { mx[r] = -1e30f; ls[r] = 0.f; }

  // stage K/V tile t0 into buffer buf with pre-swizzled global source
  auto stage = [&](int buf, int t0) {
#pragma unroll
    for (int shot = 0; shot < 2; ++shot) {
      int ci = shot * 256 + tid;
      int row = ci >> 3, seg = ci & 7;
      int sseg = seg ^ (row & 7);
      gll16(Kh + (size_t)(t0 + row) * 64 + sseg * 8, &Ks[buf][ci * 8]);
      gll16(Vh + (size_t)row * 2048 + t0 + sseg * 8, &Vs[buf][ci * 8]);
    }
  };

  stage(0, 0);
  int cur = 0;
  for (int t0 = 0; t0 < 2048; t0 += 64) {
    __syncthreads();  // drains vmcnt: buf[cur] ready; all prior LDS reads done
    if (t0 + 64 < 2048) stage(cur ^ 1, t0 + 64);  // prefetch hides under compute

    // S = Q K^T (scale*log2e folded into Q). Lane: rows q=g*4+r, col t=nb*16+c.
    f32x4 s[4] = {};
    __builtin_amdgcn_s_setprio(1);
#pragma unroll
    for (int kk = 0; kk < 2; ++kk) {
      bf16x8 kf[4];
#pragma unroll
      for (int nb = 0; nb < 4; ++nb) {
        int row = nb * 16 + c;
        kf[nb] = *(const bf16x8*)&Ks[cur][row * 64 + (((kk * 4 + g) ^ (row & 7)) * 8)];
      }
#pragma unroll
      for (int nb = 0; nb < 4; ++nb) s[nb] = mfma16(qf[kk], kf[nb], s[nb]);
    }
    __builtin_amdgcn_s_setprio(0);

    // online softmax in log2 domain; defer rescale unless max grew > 8
    float tm[4];
#pragma unroll
    for (int r = 0; r < 4; ++r) {
      float t = fmaxf(fmaxf(s[0][r], s[1][r]), fmaxf(s[2][r], s[3][r]));
      t = fmaxf(t, __shfl_xor(t, 1));
      t = fmaxf(t, __shfl_xor(t, 2));
      t = fmaxf(t, __shfl_xor(t, 4));
      t = fmaxf(t, __shfl_xor(t, 8));
      tm[r] = t;
    }
    float need = fmaxf(fmaxf(tm[0] - mx[0], tm[1] - mx[1]),
                       fmaxf(tm[2] - mx[2], tm[3] - mx[3]));
    if (!__all(need <= 8.0f)) {
#pragma unroll
      for (int r = 0; r < 4; ++r) {
        float mn = fmaxf(mx[r], tm[r]);
        float corr = exp2f(mx[r] - mn);
        ls[r] *= corr;
#pragma unroll
        for (int db = 0; db < 4; ++db) acc[db][r] *= corr;
        mx[r] = mn;
      }
    }
#pragma unroll
    for (int r = 0; r < 4; ++r) {
      int prow = w * 16 + g * 4 + r;
      float ps = 0.f;
#pragma unroll
      for (int nb = 0; nb < 4; ++nb) {
        float p = exp2f(s[nb][r] - mx[r]);
        ps += p;
        int seg = nb * 2 + (c >> 3);
        Ps[prow * 64 + ((seg ^ (prow & 7)) * 8) + (c & 7)] = f2b(p);
      }
      ls[r] += ps;
    }

    // Y += P V
    __builtin_amdgcn_s_setprio(1);
#pragma unroll
    for (int kk = 0; kk < 2; ++kk) {
      int prr = w * 16 + c;
      bf16x8 pf = *(const bf16x8*)&Ps[prr * 64 + (((kk * 4 + g) ^ (prr & 7)) * 8)];
#pragma unroll
      for (int db = 0; db < 4; ++db) {
        int row = db * 16 + c;
        bf16x8 vf = *(const bf16x8*)&Vs[cur][row * 64 + (((kk * 4 + g) ^ (row & 7)) * 8)];
        acc[db] = mfma16(pf, vf, acc[db]);
      }
    }
    __builtin_amdgcn_s_setprio(0);
    cur ^= 1;
  }

  // epilogue: y = acc / l ; Yb layout [b][t][h*64+d] bf16
#pragma unroll
  for (int r = 0; r < 4; ++r) {
    float lt = ls[r];
    lt += __shfl_xor(lt, 1);
    lt += __shfl_xor(lt, 2);
    lt += __shfl_xor(lt, 4);
    lt += __shfl_xor(lt, 8);
    float inv = 1.0f / lt;
    int trow = q0 + w * 16 + g * 4 + r;
    size_t base = ((size_t)b * 2048 + trow) * 1024 + h * 64;
#pragma unroll
    for (int db = 0; db < 4; ++db)
      Yb[base + db * 16 + c] = f2b(acc[db][r] * inv);
  }
}

// ---------------- GEMM3: out = y @ w_proj^T + b_proj (fp32 out) ----------------
__global__ __launch_bounds__(256) void gemm_proj(const u16* __restrict__ A,
                                                 const u16* __restrict__ W,
                                                 const float* __restrict__ bias,
                                                 float* __restrict__ out) {
  __shared__ u16 As[128 * 64];
  __shared__ u16 Bs[128 * 64];
  const int K = 1024;
  int bn = blockIdx.x, bm = blockIdx.y;
  int tid = threadIdx.x, lane = tid & 63, w = tid >> 6;
  int wm = w >> 1, wn = w & 1, g = lane >> 4, c = lane & 15;
  f32x4 acc[4][4] = {};
  const u16* Arow = A + (size_t)(bm * 128) * K;
  const u16* Wrow = W + (size_t)(bn * 128) * K;
  for (int k0 = 0; k0 < K; k0 += 64) {
#pragma unroll
    for (int rr = 0; rr < 4; ++rr) {
      int ci = rr * 256 + tid;
      gll16(Arow + (ci >> 3) * K + k0 + (ci & 7) * 8, As + ci * 8);
    }
#pragma unroll
    for (int rr = 0; rr < 4; ++rr) {
      int ci = rr * 256 + tid;
      gll16(Wrow + (ci >> 3) * K + k0 + (ci & 7) * 8, Bs + ci * 8);
    }
    __syncthreads();
#pragma unroll
    for (int kk = 0; kk < 2; ++kk) {
      int koff = kk * 32 + g * 8;
      bf16x8 af[4], bfr[4];
#pragma unroll
      for (int mi = 0; mi < 4; ++mi)
        af[mi] = *(const bf16x8*)&As[(wm * 64 + mi * 16 + c) * 64 + koff];
#pragma unroll
      for (int ni = 0; ni < 4; ++ni)
        bfr[ni] = *(const bf16x8*)&Bs[(wn * 64 + ni * 16 + c) * 64 + koff];
#pragma unroll
      for (int mi = 0; mi < 4; ++mi)
#pragma unroll
        for (int ni = 0; ni < 4; ++ni)
          acc[mi][ni] = mfma16(af[mi], bfr[ni], acc[mi][ni]);
    }
    __syncthreads();
  }
#pragma unroll
  for (int mi = 0; mi < 4; ++mi)
#pragma unroll
    for (int ni = 0; ni < 4; ++ni)
#pragma unroll
      for (int r = 0; r < 4; ++r) {
        int row = bm * 128 + wm * 64 + mi * 16 + g * 4 + r;
        int col = bn * 128 + wn * 64 + ni * 16 + c;
        out[(size_t)row * 1024 + col] = acc[mi][ni][r] + bias[col];
      }
}

extern "C" void kernel_launch(void* const* d_in, const int* in_sizes, int n_in,
                              void* d_out, int out_size, void* d_ws, size_t ws_size,
                              hipStream_t stream) {
  const float* x      = (const float*)d_in[0];  // [2,2048,1024]
  const float* w_attn = (const float*)d_in[1];  // [3072,1024]
  const float* b_attn = (const float*)d_in[2];  // [3072]
  const float* w_proj = (const float*)d_in[3];  // [1024,1024]
  const float* b_proj = (const float*)d_in[4];  // [1024]
  float* out = (float*)d_out;

  u16* ws = (u16*)d_ws;
  const size_t XB  = 0;                 // 4096*1024
  const size_t WAB = XB + 4194304;      // 3072*1024
  const size_t WPB = WAB + 3145728;     // 1024*1024
  const size_t QB  = WPB + 1048576;     // 2*16*2048*64
  const size_t KB  = QB + 4194304;
  const size_t VTB = KB + 4194304;      // [bh][64][2048]
  const size_t YB  = VTB + 4194304;     // 4096*1024

  cvt3<<<8192, 256, 0, stream>>>(x, w_attn, w_proj, ws + XB, ws + WAB, ws + WPB);

  gemm_qkv<<<dim3(24, 32), 256, 0, stream>>>(ws + XB, ws + WAB, b_attn,
                                             ws + QB, ws + KB, ws + VTB);

  attn_kernel<<<dim3(32, 32), 256, 0, stream>>>(ws + QB, ws + KB, ws + VTB, ws + YB);

  gemm_proj<<<dim3(8, 32), 256, 0, stream>>>(ws + YB, ws + WPB, b_proj, out);
}